// Round 5
// baseline (126.859 us; speedup 1.0000x reference)
//
#include <hip/hip_runtime.h>
#include <cstring>
#include <cstdint>

#define TGT 2048
#define NH 16
#define HD 64
#define DIM 1024
#define OD3 3072

typedef _Float16 f16x8 __attribute__((ext_vector_type(8)));
typedef _Float16 f16x4 __attribute__((ext_vector_type(4)));
typedef _Float16 f16x2 __attribute__((ext_vector_type(2)));
typedef float f32x4 __attribute__((ext_vector_type(4)));
typedef float f32x16 __attribute__((ext_vector_type(16)));

__device__ __forceinline__ void gload16(const void* g, void* l) {
  __builtin_amdgcn_global_load_lds(
      (const __attribute__((address_space(1))) unsigned int*)g,
      (__attribute__((address_space(3))) unsigned int*)l, 16, 0, 0);
}

// ---------------- fused cast f32 -> f16 (x, W_in, W_out), 8 elems/thread ----------------
__global__ void cast_all(const float* __restrict__ x, const float* __restrict__ win,
                         const float* __restrict__ wout, _Float16* __restrict__ xh,
                         _Float16* __restrict__ winh, _Float16* __restrict__ wouth) {
  const int NX = TGT * DIM / 8, NW = OD3 * DIM / 8, NO = DIM * DIM / 8;
  int i = blockIdx.x * blockDim.x + threadIdx.x;
  const float* src;
  _Float16* dst;
  int off;
  if (i < NX) { src = x; dst = xh; off = i; }
  else if (i < NX + NW) { src = win; dst = winh; off = i - NX; }
  else if (i < NX + NW + NO) { src = wout; dst = wouth; off = i - NX - NW; }
  else return;
  const float4* p = (const float4*)(src + (size_t)off * 8);
  float4 a = p[0], b = p[1];
  f16x8 o;
  o[0] = (_Float16)a.x; o[1] = (_Float16)a.y; o[2] = (_Float16)a.z; o[3] = (_Float16)a.w;
  o[4] = (_Float16)b.x; o[5] = (_Float16)b.y; o[6] = (_Float16)b.z; o[7] = (_Float16)b.w;
  *(f16x8*)(dst + (size_t)off * 8) = o;
}

// ---------------- QKV GEMM: [2048,1024]x[3072,1024]^T ----------------
// q -> qh[h][n][64].
// K -> kg[h][kt][ ((a*4+st)*64 + hi*32 + (krow&31))*8 + (d&7) ]   (a=(krow&127)>>5, st=d>>4, hi=(d>>3)&1)
// V -> vg[h][kt][ ((e*8+u)*64 + hi*32 + (d&31))*8 + (krow&7) ]    (e=d>>5, u=(krow&127)>>4, hi=(krow>>3)&1)
// These match the attention kernel's per-lane MFMA fragment order exactly.
__global__ __launch_bounds__(256) void gemm_qkv(
    const _Float16* __restrict__ A, const _Float16* __restrict__ B,
    _Float16* __restrict__ qh, _Float16* __restrict__ kg, _Float16* __restrict__ vg) {
  __shared__ __attribute__((aligned(16))) _Float16 As[2][4096];
  __shared__ __attribute__((aligned(16))) _Float16 Bs[2][4096];
  const int tid = threadIdx.x, lane = tid & 63, w = tid >> 6;
  const int g = lane >> 4, c = lane & 15;
  const int wr = w >> 1, wc = w & 1;
  const int id = blockIdx.x;                 // 384 blocks, XCD swizzle (384 = 8*48)
  const int swz = (id & 7) * 48 + (id >> 3);
  const int bm = (swz / 24) * 128, bn = (swz % 24) * 128;
  f32x4 acc[4][4] = {};

#define QKV_STAGE(buf, k0)                                                              \
  {                                                                                     \
    _Pragma("unroll") for (int t = 0; t < 2; ++t) {                                     \
      gload16(A + (size_t)(bm + t * 64 + lane) * DIM + (k0) + w * 8,                    \
              &As[buf][w * 1024 + t * 512]);                                            \
      gload16(B + (size_t)(bn + t * 64 + lane) * DIM + (k0) + w * 8,                    \
              &Bs[buf][w * 1024 + t * 512]);                                            \
    }                                                                                   \
  }

  QKV_STAGE(0, 0);
  __syncthreads();
  for (int kk = 0; kk < 32; ++kk) {
    const int cur = kk & 1;
    if (kk + 1 < 32) QKV_STAGE(cur ^ 1, (kk + 1) * 32);
    f16x8 af[4], bf[4];
#pragma unroll
    for (int m = 0; m < 4; ++m) af[m] = *(const f16x8*)(&As[cur][g * 1024 + (wr * 64 + m * 16 + c) * 8]);
#pragma unroll
    for (int n = 0; n < 4; ++n) bf[n] = *(const f16x8*)(&Bs[cur][g * 1024 + (wc * 64 + n * 16 + c) * 8]);
    __builtin_amdgcn_s_setprio(1);
#pragma unroll
    for (int m = 0; m < 4; ++m)
#pragma unroll
      for (int n = 0; n < 4; ++n)
        acc[m][n] = __builtin_amdgcn_mfma_f32_16x16x32_f16(af[m], bf[n], acc[m][n], 0, 0, 0);
    __builtin_amdgcn_s_setprio(0);
    __syncthreads();
  }
#undef QKV_STAGE

  const int which = bn >> 10;  // 0=q 1=k 2=v (uniform per block)
  const int bnn = bn & 1023;
  if (which == 0) {
#pragma unroll
    for (int m = 0; m < 4; ++m)
#pragma unroll
      for (int n = 0; n < 4; ++n)
#pragma unroll
        for (int j = 0; j < 4; ++j) {
          int row = bm + wr * 64 + m * 16 + g * 4 + j;
          int o = bnn + wc * 64 + n * 16 + c;
          qh[((size_t)(o >> 6) * TGT + row) * HD + (o & 63)] = (_Float16)acc[m][n][j];
        }
  } else if (which == 1) {
#pragma unroll
    for (int m = 0; m < 4; ++m)
#pragma unroll
      for (int n = 0; n < 4; ++n)
#pragma unroll
        for (int j = 0; j < 4; ++j) {
          int krow = bm + wr * 64 + m * 16 + g * 4 + j;
          int o = bnn + wc * 64 + n * 16 + c;
          int hh = o >> 6, d = o & 63;
          int kt = krow >> 7, a = (krow & 127) >> 5, r31 = krow & 31;
          int st = d >> 4, hi2 = (d >> 3) & 1, jd = d & 7;
          kg[(size_t)hh * 131072 + kt * 8192 + ((a * 4 + st) * 64 + hi2 * 32 + r31) * 8 + jd] =
              (_Float16)acc[m][n][j];
        }
  } else {
#pragma unroll
    for (int m = 0; m < 4; ++m)
#pragma unroll
      for (int n = 0; n < 4; ++n) {
        int krow0 = bm + wr * 64 + m * 16 + g * 4;  // j = 0..3 consecutive k-rows
        int o = bnn + wc * 64 + n * 16 + c;
        int hh = o >> 6, d = o & 63;
        int kt = krow0 >> 7, kr = krow0 & 127;
        int u = kr >> 4, hi2 = (kr >> 3) & 1, jb = kr & 7;  // jb in {0,4}
        int e = d >> 5, r31 = d & 31;
        f16x4 v;
#pragma unroll
        for (int j = 0; j < 4; ++j) v[j] = (_Float16)acc[m][n][j];
        *(f16x4*)(vg + (size_t)hh * 131072 + kt * 8192 +
                  ((e * 8 + u) * 64 + hi2 * 32 + r31) * 8 + jb) = v;
      }
  }
}

// ---------------- out GEMM: [2048,1024]x[1024,1024]^T -> f32 ----------------
__global__ __launch_bounds__(256) void gemm_out(
    const _Float16* __restrict__ A, const _Float16* __restrict__ B, float* __restrict__ out) {
  __shared__ __attribute__((aligned(16))) _Float16 As[2][4096];
  __shared__ __attribute__((aligned(16))) _Float16 Bs[2][4096];
  const int tid = threadIdx.x, lane = tid & 63, w = tid >> 6;
  const int g = lane >> 4, c = lane & 15;
  const int wr = w >> 1, wc = w & 1;
  const int id = blockIdx.x;                 // 128 blocks = 8*16
  const int swz = (id & 7) * 16 + (id >> 3);
  const int bm = (swz / 8) * 128, bn = (swz % 8) * 128;
  f32x4 acc[4][4] = {};

#define OUT_STAGE(buf, k0)                                                              \
  {                                                                                     \
    _Pragma("unroll") for (int t = 0; t < 2; ++t) {                                     \
      gload16(A + (size_t)(bm + t * 64 + lane) * DIM + (k0) + w * 8,                    \
              &As[buf][w * 1024 + t * 512]);                                            \
      gload16(B + (size_t)(bn + t * 64 + lane) * DIM + (k0) + w * 8,                    \
              &Bs[buf][w * 1024 + t * 512]);                                            \
    }                                                                                   \
  }

  OUT_STAGE(0, 0);
  __syncthreads();
  for (int kk = 0; kk < 32; ++kk) {
    const int cur = kk & 1;
    if (kk + 1 < 32) OUT_STAGE(cur ^ 1, (kk + 1) * 32);
    f16x8 af[4], bf[4];
#pragma unroll
    for (int m = 0; m < 4; ++m) af[m] = *(const f16x8*)(&As[cur][g * 1024 + (wr * 64 + m * 16 + c) * 8]);
#pragma unroll
    for (int n = 0; n < 4; ++n) bf[n] = *(const f16x8*)(&Bs[cur][g * 1024 + (wc * 64 + n * 16 + c) * 8]);
    __builtin_amdgcn_s_setprio(1);
#pragma unroll
    for (int m = 0; m < 4; ++m)
#pragma unroll
      for (int n = 0; n < 4; ++n)
        acc[m][n] = __builtin_amdgcn_mfma_f32_16x16x32_f16(af[m], bf[n], acc[m][n], 0, 0, 0);
    __builtin_amdgcn_s_setprio(0);
    __syncthreads();
  }
#undef OUT_STAGE

#pragma unroll
  for (int m = 0; m < 4; ++m)
#pragma unroll
    for (int n = 0; n < 4; ++n)
#pragma unroll
      for (int j = 0; j < 4; ++j) {
        int row = bm + wr * 64 + m * 16 + g * 4 + j;
        int o = bn + wc * 64 + n * 16 + c;
        out[(size_t)row * DIM + o] = acc[m][n][j];
      }
}

// ---------------- flash attention, 32x32 MFMA, 2 waves x 32 q-rows, KB=128 ----------------
// S^T = mfma32(K, Q): lane holds S[q=lane&31][k = 32a + (r&3)+8*(r>>2)+4*hi], r=0..15.
// Row stats fully lane-local + one shfl_xor(32).
// P repack to PV B-frag: per a: 8 cvt_pkrtz + 4 shfl_xor(32) + cndmask (all static indices).
// PV: ctx^T = mfma32(V^T, P), accum 2 x f32x16; m/l/alpha per-lane scalars; T13 defer-max.
__global__ __launch_bounds__(128) void attn(
    const _Float16* __restrict__ qh, const _Float16* __restrict__ kg,
    const _Float16* __restrict__ vg, _Float16* __restrict__ ctxh, float scal2) {
  __shared__ __attribute__((aligned(16))) _Float16 Ks[2][8192];
  __shared__ __attribute__((aligned(16))) _Float16 Vs[2][8192];
  const int tid = threadIdx.x, lane = tid & 63, w = tid >> 6;
  const int l31 = lane & 31, hi = lane >> 5;
  const int h = blockIdx.y;
  const int q0 = blockIdx.x * 64;
  const int qrow = q0 + w * 32 + l31;
  const _Float16* kbase = kg + (size_t)h * 131072;
  const _Float16* vbase = vg + (size_t)h * 131072;

  f16x8 qf[4];
#pragma unroll
  for (int st = 0; st < 4; ++st)
    qf[st] = *(const f16x8*)(qh + ((size_t)h * TGT + qrow) * HD + st * 16 + hi * 8);

  float m2 = -INFINITY, lsum = 0.f;
  f32x16 o0 = {}, o1 = {};

#define ATTN_STAGE(buf, kt)                                                    \
  {                                                                            \
    _Pragma("unroll") for (int t = 0; t < 8; ++t) {                            \
      int chunk = t * 128 + tid;                                               \
      gload16(kbase + (size_t)(kt) * 8192 + chunk * 8, &Ks[buf][chunk * 8]);   \
      gload16(vbase + (size_t)(kt) * 8192 + chunk * 8, &Vs[buf][chunk * 8]);   \
    }                                                                          \
  }

  ATTN_STAGE(0, 0);
  __syncthreads();

  for (int kt = 0; kt < TGT / 128; ++kt) {
    const int cur = kt & 1;
    if (kt + 1 < TGT / 128) ATTN_STAGE(cur ^ 1, kt + 1);

    // S^T = K Q^T
    f32x16 sa[4] = {};
    __builtin_amdgcn_s_setprio(1);
#pragma unroll
    for (int a = 0; a < 4; ++a)
#pragma unroll
      for (int st = 0; st < 4; ++st) {
        f16x8 kf = *(const f16x8*)(&Ks[cur][((a * 4 + st) * 64 + lane) * 8]);
        sa[a] = __builtin_amdgcn_mfma_f32_32x32x16_f16(kf, qf[st], sa[a], 0, 0, 0);
      }
    __builtin_amdgcn_s_setprio(0);

    // row max: 63 in-lane fmax + one cross-half shuffle
    float mx = sa[0][0];
#pragma unroll
    for (int a = 0; a < 4; ++a)
#pragma unroll
      for (int r = 0; r < 16; ++r) mx = fmaxf(mx, sa[a][r]);
    mx = fmaxf(mx, __shfl_xor(mx, 32));
    float pmax = mx * scal2;  // log2 domain

    if (!__all(pmax <= m2 + 8.f)) {  // T13 defer-max
      float mnew = fmaxf(m2, pmax);
      float alpha = __builtin_amdgcn_exp2f(m2 - mnew);
      m2 = mnew;
      lsum *= alpha;
#pragma unroll
      for (int r = 0; r < 16; ++r) { o0[r] *= alpha; o1[r] *= alpha; }
    }

    float tsum = 0.f;
#pragma unroll
    for (int a = 0; a < 4; ++a) {
      float p[16];
#pragma unroll
      for (int r = 0; r < 16; ++r)
        p[r] = __builtin_amdgcn_exp2f(__builtin_fmaf(sa[a][r], scal2, -m2));
#pragma unroll
      for (int r = 0; r < 16; ++r) tsum += p[r];
      uint32_t pkL[4][2];
#pragma unroll
      for (int r1 = 0; r1 < 4; ++r1)
#pragma unroll
        for (int pp = 0; pp < 2; ++pp) {
          auto pr = __builtin_amdgcn_cvt_pkrtz(p[4 * r1 + 2 * pp], p[4 * r1 + 2 * pp + 1]);
          memcpy(&pkL[r1][pp], &pr, 4);
        }
#pragma unroll
      for (int ul = 0; ul < 2; ++ul) {
        const int u = 2 * a + ul;
        uint32_t lo0 = pkL[2 * ul][0], lo1 = pkL[2 * ul][1];
        uint32_t hi0 = pkL[2 * ul + 1][0], hi1 = pkL[2 * ul + 1][1];
        uint32_t send0 = hi ? lo0 : hi0, send1 = hi ? lo1 : hi1;
        uint32_t keep0 = hi ? hi0 : lo0, keep1 = hi ? hi1 : lo1;
        uint32_t recv0 = (uint32_t)__shfl_xor((int)send0, 32);
        uint32_t recv1 = (uint32_t)__shfl_xor((int)send1, 32);
        uint32_t fr[4];
        fr[0] = hi ? recv0 : keep0;  // fromH0
        fr[1] = hi ? recv1 : keep1;
        fr[2] = hi ? keep0 : recv0;  // fromH1
        fr[3] = hi ? keep1 : recv1;
        f16x8 pa;
        memcpy(&pa, fr, 16);
        __builtin_amdgcn_s_setprio(1);
        {
          f16x8 v0 = *(const f16x8*)(&Vs[cur][((0 * 8 + u) * 64 + lane) * 8]);
          o0 = __builtin_amdgcn_mfma_f32_32x32x16_f16(v0, pa, o0, 0, 0, 0);
          f16x8 v1 = *(const f16x8*)(&Vs[cur][((1 * 8 + u) * 64 + lane) * 8]);
          o1 = __builtin_amdgcn_mfma_f32_32x32x16_f16(v1, pa, o1, 0, 0, 0);
        }
        __builtin_amdgcn_s_setprio(0);
      }
    }
    tsum += __shfl_xor(tsum, 32);
    lsum += tsum;
    __syncthreads();
  }
#undef ATTN_STAGE

  // epilogue: o{e}[r] = ctx[q=qrow][d = 32e + (r&3) + 8*(r>>2) + 4*hi]
  float inv = 1.0f / lsum;
#pragma unroll
  for (int rq = 0; rq < 4; ++rq) {
    f16x4 va, vb;
#pragma unroll
    for (int j = 0; j < 4; ++j) {
      va[j] = (_Float16)(o0[rq * 4 + j] * inv);
      vb[j] = (_Float16)(o1[rq * 4 + j] * inv);
    }
    _Float16* base = ctxh + (size_t)qrow * DIM + h * HD;
    *(f16x4*)(base + 8 * rq + 4 * hi) = va;
    *(f16x4*)(base + 32 + 8 * rq + 4 * hi) = vb;
  }
}

// ---------------- host ----------------
static float fp16_round_host(float x) {
  uint32_t u; memcpy(&u, &x, 4);
  uint32_t sign = u & 0x80000000u;
  uint32_t exp = (u >> 23) & 0xff;
  uint32_t m = u & 0x7fffffu;
  uint32_t low = m & 0x1fffu, hi = m >> 13;
  if (low > 0x1000u || (low == 0x1000u && (hi & 1))) hi++;
  if (hi == 0x400u) { hi = 0; exp++; }
  uint32_t r = sign | (exp << 23) | (hi << 13);
  float f; memcpy(&f, &r, 4); return f;
}

extern "C" void kernel_launch(void* const* d_in, const int* in_sizes, int n_in,
                              void* d_out, int out_size, void* d_ws, size_t ws_size,
                              hipStream_t stream) {
  const float* x = (const float*)d_in[0];
  const float* Win = (const float*)d_in[1];
  const float* Wout = (const float*)d_in[2];
  float* out = (float*)d_out;
  char* ws = (char*)d_ws;
  _Float16* xh    = (_Float16*)(ws);
  _Float16* winh  = (_Float16*)(ws + (4ull << 20));
  _Float16* wouth = (_Float16*)(ws + (10ull << 20));
  _Float16* qh    = (_Float16*)(ws + (12ull << 20));
  _Float16* kg    = (_Float16*)(ws + (16ull << 20));
  _Float16* vg    = (_Float16*)(ws + (20ull << 20));
  _Float16* ctxh  = (_Float16*)(ws + (24ull << 20));

  // Quake fast-rsqrt(64) with one Newton step, fp32 ops in numpy order, then fp16 round.
  float y = 64.0f;
  volatile float x2 = 32.0f;
  int ib; memcpy(&ib, &y, 4);
  ib = 1597463007 - (ib >> 1);
  memcpy(&y, &ib, 4);
  volatile float t1 = x2 * y;
  volatile float t2 = t1 * y;
  volatile float t3 = 1.5f - t2;
  y = y * t3;
  const float scaling = fp16_round_host(y);
  const float scal2 = scaling * 1.4426950408889634f;  // * log2(e)

  const int ncast = (TGT * DIM + OD3 * DIM + DIM * DIM) / 8;
  cast_all<<<(ncast + 255) / 256, 256, 0, stream>>>(x, Win, Wout, xh, winh, wouth);
  gemm_qkv<<<384, 256, 0, stream>>>(xh, winh, qh, kg, vg);
  attn<<<dim3(TGT / 64, NH), 128, 0, stream>>>(qh, kg, vg, ctxh, scal2);
  gemm_out<<<128, 256, 0, stream>>>(ctxh, wouth, out);
}

// Round 6
// 118.518 us; speedup vs baseline: 1.0704x; 1.0704x over previous
//
#include <hip/hip_runtime.h>
#include <cstring>
#include <cstdint>

#define TGT 2048
#define NH 16
#define HD 64
#define DIM 1024
#define OD3 3072

typedef _Float16 f16x8 __attribute__((ext_vector_type(8)));
typedef _Float16 f16x4 __attribute__((ext_vector_type(4)));
typedef _Float16 f16x2 __attribute__((ext_vector_type(2)));
typedef float f32x4 __attribute__((ext_vector_type(4)));
typedef float f32x16 __attribute__((ext_vector_type(16)));

__device__ __forceinline__ void gload16(const void* g, void* l) {
  __builtin_amdgcn_global_load_lds(
      (const __attribute__((address_space(1))) unsigned int*)g,
      (__attribute__((address_space(3))) unsigned int*)l, 16, 0, 0);
}

// ---------------- fused cast f32 -> f16 (x, W_in, W_out), 8 elems/thread ----------------
__global__ void cast_all(const float* __restrict__ x, const float* __restrict__ win,
                         const float* __restrict__ wout, _Float16* __restrict__ xh,
                         _Float16* __restrict__ winh, _Float16* __restrict__ wouth) {
  const int NX = TGT * DIM / 8, NW = OD3 * DIM / 8, NO = DIM * DIM / 8;
  int i = blockIdx.x * blockDim.x + threadIdx.x;
  const float* src;
  _Float16* dst;
  int off;
  if (i < NX) { src = x; dst = xh; off = i; }
  else if (i < NX + NW) { src = win; dst = winh; off = i - NX; }
  else if (i < NX + NW + NO) { src = wout; dst = wouth; off = i - NX - NW; }
  else return;
  const float4* p = (const float4*)(src + (size_t)off * 8);
  float4 a = p[0], b = p[1];
  f16x8 o;
  o[0] = (_Float16)a.x; o[1] = (_Float16)a.y; o[2] = (_Float16)a.z; o[3] = (_Float16)a.w;
  o[4] = (_Float16)b.x; o[5] = (_Float16)b.y; o[6] = (_Float16)b.z; o[7] = (_Float16)b.w;
  *(f16x8*)(dst + (size_t)off * 8) = o;
}

// ---------------- QKV GEMM: [2048,1024]x[3072,1024]^T ----------------
// q -> qh[h][n][64].
// K -> kg[h][kt][ ((a*4+st)*64 + hi*32 + (krow&31))*8 + (d&7) ]
// V -> vg[h][kt][ ((e*8+u)*64 + hi*32 + (d&31))*8 + (krow&7) ]
__global__ __launch_bounds__(256) void gemm_qkv(
    const _Float16* __restrict__ A, const _Float16* __restrict__ B,
    _Float16* __restrict__ qh, _Float16* __restrict__ kg, _Float16* __restrict__ vg) {
  __shared__ __attribute__((aligned(16))) _Float16 As[2][4096];
  __shared__ __attribute__((aligned(16))) _Float16 Bs[2][4096];
  const int tid = threadIdx.x, lane = tid & 63, w = tid >> 6;
  const int g = lane >> 4, c = lane & 15;
  const int wr = w >> 1, wc = w & 1;
  const int id = blockIdx.x;                 // 384 blocks, XCD swizzle (384 = 8*48)
  const int swz = (id & 7) * 48 + (id >> 3);
  const int bm = (swz / 24) * 128, bn = (swz % 24) * 128;
  f32x4 acc[4][4] = {};

#define QKV_STAGE(buf, k0)                                                              \
  {                                                                                     \
    _Pragma("unroll") for (int t = 0; t < 2; ++t) {                                     \
      gload16(A + (size_t)(bm + t * 64 + lane) * DIM + (k0) + w * 8,                    \
              &As[buf][w * 1024 + t * 512]);                                            \
      gload16(B + (size_t)(bn + t * 64 + lane) * DIM + (k0) + w * 8,                    \
              &Bs[buf][w * 1024 + t * 512]);                                            \
    }                                                                                   \
  }

  QKV_STAGE(0, 0);
  __syncthreads();
  for (int kk = 0; kk < 32; ++kk) {
    const int cur = kk & 1;
    if (kk + 1 < 32) QKV_STAGE(cur ^ 1, (kk + 1) * 32);
    f16x8 af[4], bf[4];
#pragma unroll
    for (int m = 0; m < 4; ++m) af[m] = *(const f16x8*)(&As[cur][g * 1024 + (wr * 64 + m * 16 + c) * 8]);
#pragma unroll
    for (int n = 0; n < 4; ++n) bf[n] = *(const f16x8*)(&Bs[cur][g * 1024 + (wc * 64 + n * 16 + c) * 8]);
    __builtin_amdgcn_s_setprio(1);
#pragma unroll
    for (int m = 0; m < 4; ++m)
#pragma unroll
      for (int n = 0; n < 4; ++n)
        acc[m][n] = __builtin_amdgcn_mfma_f32_16x16x32_f16(af[m], bf[n], acc[m][n], 0, 0, 0);
    __builtin_amdgcn_s_setprio(0);
    __syncthreads();
  }
#undef QKV_STAGE

  const int which = bn >> 10;  // 0=q 1=k 2=v (uniform per block)
  const int bnn = bn & 1023;
  if (which == 0) {
#pragma unroll
    for (int m = 0; m < 4; ++m)
#pragma unroll
      for (int n = 0; n < 4; ++n)
#pragma unroll
        for (int j = 0; j < 4; ++j) {
          int row = bm + wr * 64 + m * 16 + g * 4 + j;
          int o = bnn + wc * 64 + n * 16 + c;
          qh[((size_t)(o >> 6) * TGT + row) * HD + (o & 63)] = (_Float16)acc[m][n][j];
        }
  } else if (which == 1) {
#pragma unroll
    for (int m = 0; m < 4; ++m)
#pragma unroll
      for (int n = 0; n < 4; ++n)
#pragma unroll
        for (int j = 0; j < 4; ++j) {
          int krow = bm + wr * 64 + m * 16 + g * 4 + j;
          int o = bnn + wc * 64 + n * 16 + c;
          int hh = o >> 6, d = o & 63;
          int kt = krow >> 7, a = (krow & 127) >> 5, r31 = krow & 31;
          int st = d >> 4, hi2 = (d >> 3) & 1, jd = d & 7;
          kg[(size_t)hh * 131072 + kt * 8192 + ((a * 4 + st) * 64 + hi2 * 32 + r31) * 8 + jd] =
              (_Float16)acc[m][n][j];
        }
  } else {
#pragma unroll
    for (int m = 0; m < 4; ++m)
#pragma unroll
      for (int n = 0; n < 4; ++n) {
        int krow0 = bm + wr * 64 + m * 16 + g * 4;
        int o = bnn + wc * 64 + n * 16 + c;
        int hh = o >> 6, d = o & 63;
        int kt = krow0 >> 7, kr = krow0 & 127;
        int u = kr >> 4, hi2 = (kr >> 3) & 1, jb = kr & 7;
        int e = d >> 5, r31 = d & 31;
        f16x4 v;
#pragma unroll
        for (int j = 0; j < 4; ++j) v[j] = (_Float16)acc[m][n][j];
        *(f16x4*)(vg + (size_t)hh * 131072 + kt * 8192 +
                  ((e * 8 + u) * 64 + hi2 * 32 + r31) * 8 + jb) = v;
      }
  }
}

// ---------------- out GEMM: [2048,1024]x[1024,1024]^T -> f32 ----------------
__global__ __launch_bounds__(256) void gemm_out(
    const _Float16* __restrict__ A, const _Float16* __restrict__ B, float* __restrict__ out) {
  __shared__ __attribute__((aligned(16))) _Float16 As[2][4096];
  __shared__ __attribute__((aligned(16))) _Float16 Bs[2][4096];
  const int tid = threadIdx.x, lane = tid & 63, w = tid >> 6;
  const int g = lane >> 4, c = lane & 15;
  const int wr = w >> 1, wc = w & 1;
  const int id = blockIdx.x;                 // 128 blocks = 8*16
  const int swz = (id & 7) * 16 + (id >> 3);
  const int bm = (swz / 8) * 128, bn = (swz % 8) * 128;
  f32x4 acc[4][4] = {};

#define OUT_STAGE(buf, k0)                                                              \
  {                                                                                     \
    _Pragma("unroll") for (int t = 0; t < 2; ++t) {                                     \
      gload16(A + (size_t)(bm + t * 64 + lane) * DIM + (k0) + w * 8,                    \
              &As[buf][w * 1024 + t * 512]);                                            \
      gload16(B + (size_t)(bn + t * 64 + lane) * DIM + (k0) + w * 8,                    \
              &Bs[buf][w * 1024 + t * 512]);                                            \
    }                                                                                   \
  }

  OUT_STAGE(0, 0);
  __syncthreads();
  for (int kk = 0; kk < 32; ++kk) {
    const int cur = kk & 1;
    if (kk + 1 < 32) OUT_STAGE(cur ^ 1, (kk + 1) * 32);
    f16x8 af[4], bf[4];
#pragma unroll
    for (int m = 0; m < 4; ++m) af[m] = *(const f16x8*)(&As[cur][g * 1024 + (wr * 64 + m * 16 + c) * 8]);
#pragma unroll
    for (int n = 0; n < 4; ++n) bf[n] = *(const f16x8*)(&Bs[cur][g * 1024 + (wc * 64 + n * 16 + c) * 8]);
    __builtin_amdgcn_s_setprio(1);
#pragma unroll
    for (int m = 0; m < 4; ++m)
#pragma unroll
      for (int n = 0; n < 4; ++n)
        acc[m][n] = __builtin_amdgcn_mfma_f32_16x16x32_f16(af[m], bf[n], acc[m][n], 0, 0, 0);
    __builtin_amdgcn_s_setprio(0);
    __syncthreads();
  }
#undef OUT_STAGE

#pragma unroll
  for (int m = 0; m < 4; ++m)
#pragma unroll
    for (int n = 0; n < 4; ++n)
#pragma unroll
      for (int j = 0; j < 4; ++j) {
        int row = bm + wr * 64 + m * 16 + g * 4 + j;
        int o = bn + wc * 64 + n * 16 + c;
        out[(size_t)row * DIM + o] = acc[m][n][j];
      }
}

// ---------------- flash attention, 32x32 MFMA, split-K x2 ----------------
// Grid: (qblk 0..15, head 0..15, ks 0..1). Block: 4 waves x 32 q-rows (QB=128).
// Each block covers k in [ks*1024, ks*1024+1024) = 8 tiles of 128.
// Writes unnormalized partial o (f32) + (m, l) per q-row; attn_combine merges.
__global__ __launch_bounds__(256) void attn(
    const _Float16* __restrict__ qh, const _Float16* __restrict__ kg,
    const _Float16* __restrict__ vg, float* __restrict__ po, float* __restrict__ pml,
    float scal2) {
  __shared__ __attribute__((aligned(16))) _Float16 Ks[2][8192];
  __shared__ __attribute__((aligned(16))) _Float16 Vs[2][8192];
  const int tid = threadIdx.x, lane = tid & 63, w = tid >> 6;
  const int l31 = lane & 31, hi = lane >> 5;
  const int h = blockIdx.y;
  const int qblk = blockIdx.x;
  const int ks = blockIdx.z;
  const int qrow = qblk * 128 + w * 32 + l31;
  const _Float16* kbase = kg + (size_t)h * 131072 + (size_t)ks * 65536;
  const _Float16* vbase = vg + (size_t)h * 131072 + (size_t)ks * 65536;

  f16x8 qf[4];
#pragma unroll
  for (int st = 0; st < 4; ++st)
    qf[st] = *(const f16x8*)(qh + ((size_t)h * TGT + qrow) * HD + st * 16 + hi * 8);

  float m2 = -INFINITY, lsum = 0.f;
  f32x16 o0 = {}, o1 = {};

#define ATTN_STAGE(buf, kt)                                                    \
  {                                                                            \
    _Pragma("unroll") for (int t = 0; t < 4; ++t) {                            \
      int chunk = t * 256 + tid;                                               \
      gload16(kbase + (size_t)(kt) * 8192 + chunk * 8, &Ks[buf][chunk * 8]);   \
      gload16(vbase + (size_t)(kt) * 8192 + chunk * 8, &Vs[buf][chunk * 8]);   \
    }                                                                          \
  }

  ATTN_STAGE(0, 0);
  __syncthreads();

  for (int kt = 0; kt < 8; ++kt) {
    const int cur = kt & 1;
    if (kt + 1 < 8) ATTN_STAGE(cur ^ 1, kt + 1);

    // S^T = K Q^T
    f32x16 sa[4] = {};
    __builtin_amdgcn_s_setprio(1);
#pragma unroll
    for (int a = 0; a < 4; ++a)
#pragma unroll
      for (int st = 0; st < 4; ++st) {
        f16x8 kf = *(const f16x8*)(&Ks[cur][((a * 4 + st) * 64 + lane) * 8]);
        sa[a] = __builtin_amdgcn_mfma_f32_32x32x16_f16(kf, qf[st], sa[a], 0, 0, 0);
      }
    __builtin_amdgcn_s_setprio(0);

    // row max: in-lane fmax + one cross-half shuffle
    float mx = sa[0][0];
#pragma unroll
    for (int a = 0; a < 4; ++a)
#pragma unroll
      for (int r = 0; r < 16; ++r) mx = fmaxf(mx, sa[a][r]);
    mx = fmaxf(mx, __shfl_xor(mx, 32));
    float pmax = mx * scal2;  // log2 domain

    if (!__all(pmax <= m2 + 8.f)) {  // T13 defer-max
      float mnew = fmaxf(m2, pmax);
      float alpha = __builtin_amdgcn_exp2f(m2 - mnew);
      m2 = mnew;
      lsum *= alpha;
#pragma unroll
      for (int r = 0; r < 16; ++r) { o0[r] *= alpha; o1[r] *= alpha; }
    }

    float tsum = 0.f;
#pragma unroll
    for (int a = 0; a < 4; ++a) {
      float p[16];
#pragma unroll
      for (int r = 0; r < 16; ++r)
        p[r] = __builtin_amdgcn_exp2f(__builtin_fmaf(sa[a][r], scal2, -m2));
#pragma unroll
      for (int r = 0; r < 16; ++r) tsum += p[r];
      uint32_t pkL[4][2];
#pragma unroll
      for (int r1 = 0; r1 < 4; ++r1)
#pragma unroll
        for (int pp = 0; pp < 2; ++pp) {
          auto pr = __builtin_amdgcn_cvt_pkrtz(p[4 * r1 + 2 * pp], p[4 * r1 + 2 * pp + 1]);
          memcpy(&pkL[r1][pp], &pr, 4);
        }
#pragma unroll
      for (int ul = 0; ul < 2; ++ul) {
        const int u = 2 * a + ul;
        uint32_t lo0 = pkL[2 * ul][0], lo1 = pkL[2 * ul][1];
        uint32_t hi0 = pkL[2 * ul + 1][0], hi1 = pkL[2 * ul + 1][1];
        uint32_t send0 = hi ? lo0 : hi0, send1 = hi ? lo1 : hi1;
        uint32_t keep0 = hi ? hi0 : lo0, keep1 = hi ? hi1 : lo1;
        uint32_t recv0 = (uint32_t)__shfl_xor((int)send0, 32);
        uint32_t recv1 = (uint32_t)__shfl_xor((int)send1, 32);
        uint32_t fr[4];
        fr[0] = hi ? recv0 : keep0;
        fr[1] = hi ? recv1 : keep1;
        fr[2] = hi ? keep0 : recv0;
        fr[3] = hi ? keep1 : recv1;
        f16x8 pa;
        memcpy(&pa, fr, 16);
        __builtin_amdgcn_s_setprio(1);
        {
          f16x8 v0 = *(const f16x8*)(&Vs[cur][((0 * 8 + u) * 64 + lane) * 8]);
          o0 = __builtin_amdgcn_mfma_f32_32x32x16_f16(v0, pa, o0, 0, 0, 0);
          f16x8 v1 = *(const f16x8*)(&Vs[cur][((1 * 8 + u) * 64 + lane) * 8]);
          o1 = __builtin_amdgcn_mfma_f32_32x32x16_f16(v1, pa, o1, 0, 0, 0);
        }
        __builtin_amdgcn_s_setprio(0);
      }
    }
    tsum += __shfl_xor(tsum, 32);
    lsum += tsum;
    __syncthreads();
  }
#undef ATTN_STAGE

  // write partials: po[ks][h][qblk][qr][d], pml[ks][h][qblk][qr][2]
  const size_t pbase = ((((size_t)ks * 16 + h) * 16 + qblk) * 128 + (w * 32 + l31)) * 64;
#pragma unroll
  for (int rq = 0; rq < 4; ++rq) {
    f32x4 va, vb;
#pragma unroll
    for (int j = 0; j < 4; ++j) { va[j] = o0[rq * 4 + j]; vb[j] = o1[rq * 4 + j]; }
    *(f32x4*)(po + pbase + 8 * rq + 4 * hi) = va;
    *(f32x4*)(po + pbase + 32 + 8 * rq + 4 * hi) = vb;
  }
  if (hi == 0) {
    const size_t sbase = ((((size_t)ks * 16 + h) * 16 + qblk) * 128 + (w * 32 + l31)) * 2;
    pml[sbase] = m2;
    pml[sbase + 1] = lsum;
  }
}

// ---------------- combine the two k-half partials -> ctxh (f16) ----------------
__global__ void attn_combine(const float* __restrict__ po, const float* __restrict__ pml,
                             _Float16* __restrict__ ctxh) {
  int i = blockIdx.x * blockDim.x + threadIdx.x;  // 131072 = 2048*16*4
  int dq = i & 3, hq = i >> 2;
  int h = hq & 15, q = hq >> 4;
  int qblk = q >> 7, qr = q & 127;
  size_t o0b = (((size_t)0 * 16 + h) * 16 + qblk) * 8192 + (size_t)qr * 64 + dq * 16;
  size_t o1b = (((size_t)1 * 16 + h) * 16 + qblk) * 8192 + (size_t)qr * 64 + dq * 16;
  size_t s0 = ((((size_t)0 * 16 + h) * 16 + qblk) * 128 + qr) * 2;
  size_t s1 = ((((size_t)1 * 16 + h) * 16 + qblk) * 128 + qr) * 2;
  float m0 = pml[s0], l0 = pml[s0 + 1];
  float m1 = pml[s1], l1 = pml[s1 + 1];
  float m = fmaxf(m0, m1);
  float e0 = __builtin_amdgcn_exp2f(m0 - m);
  float e1 = __builtin_amdgcn_exp2f(m1 - m);
  float inv = 1.0f / (l0 * e0 + l1 * e1);
  f16x8 out2[2];
#pragma unroll
  for (int t = 0; t < 2; ++t) {
    f32x4 a0 = *(const f32x4*)(po + o0b + t * 8);
    f32x4 a4 = *(const f32x4*)(po + o0b + t * 8 + 4);
    f32x4 b0 = *(const f32x4*)(po + o1b + t * 8);
    f32x4 b4 = *(const f32x4*)(po + o1b + t * 8 + 4);
#pragma unroll
    for (int j = 0; j < 4; ++j) {
      out2[t][j] = (_Float16)((a0[j] * e0 + b0[j] * e1) * inv);
      out2[t][j + 4] = (_Float16)((a4[j] * e0 + b4[j] * e1) * inv);
    }
  }
  _Float16* dst = ctxh + (size_t)q * DIM + h * HD + dq * 16;
  *(f16x8*)(dst) = out2[0];
  *(f16x8*)(dst + 8) = out2[1];
}

// ---------------- host ----------------
static float fp16_round_host(float x) {
  uint32_t u; memcpy(&u, &x, 4);
  uint32_t sign = u & 0x80000000u;
  uint32_t exp = (u >> 23) & 0xff;
  uint32_t m = u & 0x7fffffu;
  uint32_t low = m & 0x1fffu, hi = m >> 13;
  if (low > 0x1000u || (low == 0x1000u && (hi & 1))) hi++;
  if (hi == 0x400u) { hi = 0; exp++; }
  uint32_t r = sign | (exp << 23) | (hi << 13);
  float f; memcpy(&f, &r, 4); return f;
}

extern "C" void kernel_launch(void* const* d_in, const int* in_sizes, int n_in,
                              void* d_out, int out_size, void* d_ws, size_t ws_size,
                              hipStream_t stream) {
  const float* x = (const float*)d_in[0];
  const float* Win = (const float*)d_in[1];
  const float* Wout = (const float*)d_in[2];
  float* out = (float*)d_out;
  char* ws = (char*)d_ws;
  _Float16* xh    = (_Float16*)(ws);
  _Float16* winh  = (_Float16*)(ws + (4ull << 20));
  _Float16* wouth = (_Float16*)(ws + (10ull << 20));
  _Float16* qh    = (_Float16*)(ws + (12ull << 20));
  _Float16* kg    = (_Float16*)(ws + (16ull << 20));
  _Float16* vg    = (_Float16*)(ws + (20ull << 20));
  _Float16* ctxh  = (_Float16*)(ws + (24ull << 20));
  float*    po    = (float*)(ws + (28ull << 20));    // 16 MB
  float*    pml   = (float*)(ws + (44ull << 20));    // 1 MB

  // Quake fast-rsqrt(64) with one Newton step, fp32 ops in numpy order, then fp16 round.
  float y = 64.0f;
  volatile float x2 = 32.0f;
  int ib; memcpy(&ib, &y, 4);
  ib = 1597463007 - (ib >> 1);
  memcpy(&y, &ib, 4);
  volatile float t1 = x2 * y;
  volatile float t2 = t1 * y;
  volatile float t3 = 1.5f - t2;
  y = y * t3;
  const float scaling = fp16_round_host(y);
  const float scal2 = scaling * 1.4426950408889634f;  // * log2(e)

  const int ncast = (TGT * DIM + OD3 * DIM + DIM * DIM) / 8;
  cast_all<<<(ncast + 255) / 256, 256, 0, stream>>>(x, Win, Wout, xh, winh, wouth);
  gemm_qkv<<<384, 256, 0, stream>>>(xh, winh, qh, kg, vg);
  attn<<<dim3(16, NH, 2), 256, 0, stream>>>(qh, kg, vg, po, pml, scal2);
  attn_combine<<<512, 256, 0, stream>>>(po, pml, ctxh);
  gemm_out<<<128, 256, 0, stream>>>(ctxh, wouth, out);
}